// Round 1
// 160.899 us; speedup vs baseline: 1.0777x; 1.0777x over previous
//
#include <hip/hip_runtime.h>
#include <hip/hip_bf16.h>
#include <math.h>

// Problem constants (B=2, C=256, H=W=64, Co=256, 3x3, stride1, pad1)
#define BB 2
#define CC 256
#define HH 64
#define WW 64
#define COo 256
#define HWs 4096
#define K2 9
#define CK 2304   // C*9

typedef __attribute__((ext_vector_type(4))) float floatx4;
typedef __attribute__((ext_vector_type(8))) short shortx8;   // 8 bf16

// ---- workspace layout (float units) ----
#define O_OFF   0          // final offset  B*18*4096 = 147456 f
#define O_MASK  147456     // final modulator B*9*4096 = 73728 f
#define O_WBF   221184     // reg_w bf16 [co][ck] = 294912 f
#define O_WPK   516096     // convA weights [g2][kc8][tap9][nf2][lane][8] = 73728 f
#define O_A     589824     // A matrix bf16 [pix 8192][ck 2304] = 9437184 f
#define O_XT    10027008   // x NHWC bf16 [b][y][x][c] = 1048576 f
#define O_RT    11075584   // residual NHWC bf16 = 1048576 f
// total = 12,124,160 floats = 48.5 MB

__device__ __forceinline__ void gll16(const __hip_bfloat16* g, __hip_bfloat16* l) {
    __builtin_amdgcn_global_load_lds(
        (const __attribute__((address_space(1))) unsigned int*)g,
        (__attribute__((address_space(3))) unsigned int*)l, 16, 0, 0);
}

__device__ __forceinline__ short f2bf(float v) {
    __hip_bfloat16 h = __float2bfloat16(v);
    return *reinterpret_cast<short*>(&h);
}

__device__ __forceinline__ float bf2f(short s) {
    unsigned u = ((unsigned)(unsigned short)s) << 16;
    return __builtin_bit_cast(float, u);
}

// ---------------------------------------------------------------------------
// K0: FUSED prep = transpose (blocks 0..2047) + weight pack (blocks 2048+).
// Transpose: {x, residual} (NCHW fp32) -> {xT, resT} (NHWC bf16).
// Pack:  Wbf[co*2304+ck] = bf16(reg_w)
//        Wpk: [g2][kc8][tap9][nf2][lane64][j8], c = kc*32+(lane>>4)*8+j,
//             n = nf*16+(lane&15); g=0: off_w[n][c][tap], g=1: mod_w
// ---------------------------------------------------------------------------
__global__ __launch_bounds__(256) void prep_kernel(
    const float* __restrict__ x,
    const float* __restrict__ residual,
    const float* __restrict__ reg_w,
    const float* __restrict__ off_w,
    const float* __restrict__ mod_w,
    __hip_bfloat16* __restrict__ xT,
    __hip_bfloat16* __restrict__ resT,
    __hip_bfloat16* __restrict__ Wbf,
    __hip_bfloat16* __restrict__ Wpk)
{
    int blk = blockIdx.x;
    int t = threadIdx.x;
    if (blk < 2048) {
        // ---- transpose part (validated R6-R10 layout) ----
        int sel = blk >> 10;             // 0 = x, 1 = residual
        int bk  = blk & 1023;            // ((b*64 + y)*8 + oc)
        int oc = bk & 7;
        int y  = (bk >> 3) & 63;
        int b  = bk >> 9;
        int wo = t & 63;
        int cg = t >> 6;
        int c0 = oc * 32 + cg * 8;
        const float* src = (sel ? residual : x)
                           + ((size_t)(b * CC + c0) * HH + y) * WW + wo;
        shortx8 pk;
#pragma unroll
        for (int j = 0; j < 8; ++j) pk[j] = f2bf(src[(size_t)j * HWs]);
        __hip_bfloat16* dst = sel ? resT : xT;
        *(shortx8*)(dst + ((size_t)b * 4096 + y * 64 + wo) * 256 + c0) = pk;
    } else {
        // ---- pack part (validated R6-R10) ----
        int idx = (blk - 2048) * 256 + t;
        if (idx < CK * COo) {
            Wbf[idx] = __float2bfloat16(reg_w[idx]);
        }
        if (idx < 147456) {
            int g    = idx / 73728;
            int rem  = idx % 73728;
            int kc   = rem / 9216;
            int r2   = rem % 9216;
            int tap  = r2 / 1024;
            int r3   = r2 & 1023;
            int nf   = r3 >> 9;
            int r4   = r3 & 511;
            int lane = r4 >> 3;
            int j    = r4 & 7;
            int c    = kc * 32 + (lane >> 4) * 8 + j;
            int n    = nf * 16 + (lane & 15);
            float v = 0.f;
            if (g == 0) { if (n < 18) v = off_w[((size_t)n * CC + c) * 9 + tap]; }
            else        { if (n < 9)  v = mod_w[((size_t)n * CC + c) * 9 + tap]; }
            Wpk[idx] = __float2bfloat16(v);
        }
    }
}

// ---------------------------------------------------------------------------
// K1: DIRECT offset+modulator conv. grid = 512 (b2 x g2 x 128 tiles of 32 pix),
// block 512 = 8 waves. NEW (R11): K split 4-way across waves for occupancy —
// wave w: pixel-half ph=w&1 (16 pix), K-quarter ks=w>>1 (kc pair {2ks,2ks+1},
// all 9 taps). 18 iters/wave (was 72) of {1 A-frag 16B load (edge-masked),
// 2 coalesced B-frag loads from Wpk, 2 MFMA}. Partial accs reduced via LDS
// (exact fp32 reassociation); waves 0/1 run the bias+sigmoid epilogue.
// Occupancy: 1 -> 4 waves/SIMD over this kernel's phase.
// ---------------------------------------------------------------------------
__global__ __launch_bounds__(512) void convA2_kernel(
    const __hip_bfloat16* __restrict__ xT,
    const __hip_bfloat16* __restrict__ resT,
    const __hip_bfloat16* __restrict__ Wpk,
    const float* __restrict__ off_b,
    const float* __restrict__ mod_b,
    float* __restrict__ off_out,
    float* __restrict__ mask_out)
{
    int blk = blockIdx.x;
    int tile = blk & 127;
    int g = (blk >> 7) & 1;
    int b = blk >> 8;
    int t = threadIdx.x;
    int lane = t & 63;
    int w = t >> 6;                  // 0..7
    int ph = w & 1;                  // pixel half (16 pixels)
    int ks = w >> 1;                 // K quarter (kc pair)
    int ln = lane & 15;
    int quad = lane >> 4;

    // g=0: offset conv on residual; g=1: modulator conv on x
    const __hip_bfloat16* src = (g ? xT : resT) + (size_t)b * 4096 * 256;
    const __hip_bfloat16* wg  = Wpk + (size_t)g * 73728 + (size_t)ks * 2 * 9216;

    int pix = tile * 32 + ph * 16 + ln;   // this lane's A-row (pixel)
    int ho = pix >> 6, wo = pix & 63;

    floatx4 acc0 = (floatx4){0.f, 0.f, 0.f, 0.f};
    floatx4 acc1 = (floatx4){0.f, 0.f, 0.f, 0.f};

#pragma unroll
    for (int tap = 0; tap < 9; ++tap) {
        int ky = tap / 3, kx = tap % 3;
        int r  = ho + ky - 1;
        int cx = wo + kx - 1;
        bool v = (r >= 0) && (r < HH) && (cx >= 0) && (cx < WW);
        int hw = v ? (r * WW + cx) : 0;
        // channel base for this wave's K-quarter: c = (ks*2+kc)*32 + quad*8 + j
        const __hip_bfloat16* abase = src + (size_t)hw * 256 + quad * 8 + ks * 64;
        const __hip_bfloat16* wbase = wg + (size_t)tap * 1024 + lane * 8;
#pragma unroll
        for (int kc = 0; kc < 2; ++kc) {
            shortx8 af = *(const shortx8*)(abase + kc * 32);
            if (!v) {
                shortx8 zf = {0,0,0,0,0,0,0,0};
                af = zf;
            }
            shortx8 b0 = *(const shortx8*)(wbase + (size_t)kc * 9216);
            shortx8 b1 = *(const shortx8*)(wbase + (size_t)kc * 9216 + 512);
            acc0 = __builtin_amdgcn_mfma_f32_16x16x32_bf16(af, b0, acc0, 0, 0, 0);
            acc1 = __builtin_amdgcn_mfma_f32_16x16x32_bf16(af, b1, acc1, 0, 0, 0);
        }
    }

    // cross-wave K reduction (4 partials per pixel-half), exact fp32 adds
    __shared__ float s_red[8][64][8];    // 16 KB
    *(floatx4*)&s_red[w][lane][0] = acc0;
    *(floatx4*)&s_red[w][lane][4] = acc1;
    __syncthreads();
    if (w < 2) {                         // w == ph, ks == 0
#pragma unroll
        for (int j = 0; j < 4; ++j) {
            acc0[j] = s_red[w][lane][j]     + s_red[w + 2][lane][j]
                    + s_red[w + 4][lane][j] + s_red[w + 6][lane][j];
            acc1[j] = s_red[w][lane][4 + j]     + s_red[w + 2][lane][4 + j]
                    + s_red[w + 4][lane][4 + j] + s_red[w + 6][lane][4 + j];
        }

        // epilogue: C/D col=lane&15 (=n), row=quad*4+reg (=pixel within 16)
#pragma unroll
        for (int nf = 0; nf < 2; ++nf) {
            floatx4 a = nf ? acc1 : acc0;
            int n = nf * 16 + ln;
#pragma unroll
            for (int i2 = 0; i2 < 4; ++i2) {
                int p = tile * 32 + w * 16 + quad * 4 + i2;
                if (g == 0) {
                    if (n < 18)
                        off_out[((size_t)b * 18 + n) * HWs + p] = a[i2] + off_b[n];
                } else {
                    if (n < 9) {
                        float z = a[i2] + mod_b[n];
                        mask_out[((size_t)b * 9 + n) * HWs + p] =
                            2.f / (1.f + __expf(-z));
                    }
                }
            }
        }
    }
}

// ---------------------------------------------------------------------------
// K2: deformable gather -> bf16 A [pix][ck]. (verbatim from validated R8)
// ---------------------------------------------------------------------------
__global__ __launch_bounds__(256) void gather_kernel(
    const __hip_bfloat16* __restrict__ xT,
    const float* __restrict__ off,
    const float* __restrict__ mask,
    __hip_bfloat16* __restrict__ A)
{
    int blk = blockIdx.x;            // ((b*64 + ho)*8 + cc)
    int cc = blk & 7;
    int ho = (blk >> 3) & 63;
    int b  = blk >> 9;
    int t  = threadIdx.x;
    int wo = t & 63;
    int cg = t >> 6;

    __shared__ int   s_idx[4][K2][64];
    __shared__ float s_w  [4][K2][64];

    for (int u = t; u < K2 * 64; u += 256) {
        int k = u >> 6;
        int wv = u & 63;
        float dy = off[((((size_t)b * 18 + 2 * k    ) * HH + ho) << 6) + wv];
        float dx = off[((((size_t)b * 18 + 2 * k + 1) * HH + ho) << 6) + wv];
        float m  = mask[((((size_t)b * 9 + k) * HH + ho) << 6) + wv];
        float py = (float)(ho - 1 + k / 3) + dy;
        float px = (float)(wv - 1 + k % 3) + dx;
        float y0f = floorf(py), x0f = floorf(px);
        float wy1 = py - y0f, wx1 = px - x0f;
        float wy0 = 1.f - wy1, wx0 = 1.f - wx1;
        int y0 = (int)y0f, x0 = (int)x0f;
#pragma unroll
        for (int j = 0; j < 4; ++j) {
            int yy = y0 + (j >> 1);
            int xx = x0 + (j & 1);
            float wj = ((j == 0) ? wy0 * wx0 :
                        (j == 1) ? wy0 * wx1 :
                        (j == 2) ? wy1 * wx0 : wy1 * wx1) * m;
            bool valid = (yy >= 0) && (yy < HH) && (xx >= 0) && (xx < WW);
            s_idx[j][k][wv] = valid ? (yy * WW + xx) : 0;
            s_w  [j][k][wv] = valid ? wj : 0.f;
        }
    }
    __syncthreads();

    const __hip_bfloat16* xb = xT + (size_t)b * 4096 * 256 + cc * 32 + cg * 8;

    shortx8 outv[9];
#pragma unroll
    for (int k = 0; k < K2; ++k) {
        int   i0 = s_idx[0][k][wo], i1 = s_idx[1][k][wo];
        int   i2 = s_idx[2][k][wo], i3 = s_idx[3][k][wo];
        float w0 = s_w[0][k][wo], w1 = s_w[1][k][wo];
        float w2 = s_w[2][k][wo], w3 = s_w[3][k][wo];
        shortx8 c0 = *(const shortx8*)(xb + (size_t)i0 * 256);
        shortx8 c1 = *(const shortx8*)(xb + (size_t)i1 * 256);
        shortx8 c2 = *(const shortx8*)(xb + (size_t)i2 * 256);
        shortx8 c3 = *(const shortx8*)(xb + (size_t)i3 * 256);
#pragma unroll
        for (int j = 0; j < 8; ++j) {
            float v = w0 * bf2f(c0[j]) + w1 * bf2f(c1[j])
                    + w2 * bf2f(c2[j]) + w3 * bf2f(c3[j]);
            int idx = j * 9 + k;
            outv[idx >> 3][idx & 7] = f2bf(v);
        }
    }

    __hip_bfloat16* arow = A + (size_t)((b * 64 + ho) * 64 + wo) * CK
                             + cc * 288 + cg * 72;
#pragma unroll
    for (int m = 0; m < 9; ++m)
        *(shortx8*)(arow + m * 8) = outv[m];
}

// ---------------------------------------------------------------------------
// K3: bf16 MFMA GEMM. (validated R8 inner loop: 64Mx128N, BK=64, dbuf DMA)
// NEW (R11): bijective XCD-chunk swizzle (grid 256 = 8 XCDs x 32) so both
// nt-tiles of each mt land on the same XCD -> A-tile's second read is L2-hit.
// ---------------------------------------------------------------------------
__global__ __launch_bounds__(256) void gemm_kernel(
    const __hip_bfloat16* __restrict__ A,
    const __hip_bfloat16* __restrict__ Wbf,
    float* __restrict__ out)
{
    int blk0 = blockIdx.x;
    int blk = ((blk0 & 7) << 5) | (blk0 >> 3);   // XCD chunking, bijective on 256
    int nt = blk & 1;
    int mt = blk >> 1;              // 0..127
    int t  = threadIdx.x;
    int lane = t & 63;
    int w    = t >> 6;
    int quad = lane >> 4;
    int ln   = lane & 15;
    int wm = w & 1;                 // M half (32 rows)
    int wn = w >> 1;                // N half (64 cols)

    __shared__ __hip_bfloat16 As[2][64 * 64];    // 2 x 8 KB
    __shared__ __hip_bfloat16 Bs[2][128 * 64];   // 2 x 16 KB
    __shared__ float s_out[4][16 * 40];          // per-wave epilogue (10 KB)

    int lr8 = lane >> 3;            // 0..7 (staging row within wave's 8)
    int sub = lane & 7;             // 16B slot within 128B row
    int chk = sub ^ lr8;            // global k-chunk this lane fetches

    const __hip_bfloat16* gA = A + (size_t)(mt * 64 + w * 8 + lr8) * CK + chk * 8;
    const __hip_bfloat16* gB = Wbf + (size_t)(nt * 128 + w * 8 + lr8) * CK + chk * 8;
    int lofA = w * 512;             // elements
    int lofB = w * 512;

    floatx4 acc[2][4];
#pragma unroll
    for (int mf = 0; mf < 2; ++mf)
#pragma unroll
        for (int nf = 0; nf < 4; ++nf) acc[mf][nf] = (floatx4){0.f, 0.f, 0.f, 0.f};

#pragma unroll
    for (int h = 0; h < 2; ++h)
        gll16(gA + (size_t)(h * 32) * CK, &As[0][lofA + h * 2048]);
#pragma unroll
    for (int h = 0; h < 4; ++h)
        gll16(gB + (size_t)(h * 32) * CK, &Bs[0][lofB + h * 2048]);

    int swz = ln & 7;               // read-slot XOR key

    for (int kt = 0; kt < 36; ++kt) {
        int cur = kt & 1;
        int nxt = cur ^ 1;
        __syncthreads();                      // buf[cur] staging complete
        if (kt + 1 < 36) {
            int ko = (kt + 1) * 64;
#pragma unroll
            for (int h = 0; h < 2; ++h)
                gll16(gA + (size_t)(h * 32) * CK + ko, &As[nxt][lofA + h * 2048]);
#pragma unroll
            for (int h = 0; h < 4; ++h)
                gll16(gB + (size_t)(h * 32) * CK + ko, &Bs[nxt][lofB + h * 2048]);
        }
#pragma unroll
        for (int kh = 0; kh < 2; ++kh) {
            int slot = ((kh * 4 + quad) ^ swz) * 8;
            shortx8 af[2], bf[4];
#pragma unroll
            for (int mf = 0; mf < 2; ++mf)
                af[mf] = *(const shortx8*)
                    &As[cur][(wm * 32 + mf * 16 + ln) * 64 + slot];
#pragma unroll
            for (int nf = 0; nf < 4; ++nf)
                bf[nf] = *(const shortx8*)
                    &Bs[cur][(wn * 64 + nf * 16 + ln) * 64 + slot];
#pragma unroll
            for (int mf = 0; mf < 2; ++mf)
#pragma unroll
                for (int nf = 0; nf < 4; ++nf)
                    acc[mf][nf] = __builtin_amdgcn_mfma_f32_16x16x32_bf16(
                        af[mf], bf[nf], acc[mf][nf], 0, 0, 0);
        }
    }

    int bb = mt >> 6;
    int hw0 = (mt & 63) * 64 + wm * 32;
    float* sw = &s_out[w][0];
    int co_l = lane >> 2;
    int seg  = lane & 3;
#pragma unroll
    for (int nf = 0; nf < 4; ++nf) {
        *(floatx4*)&sw[ln * 40 + quad * 4]      = acc[0][nf];
        *(floatx4*)&sw[ln * 40 + 16 + quad * 4] = acc[1][nf];
        floatx4 v0 = *(const floatx4*)&sw[co_l * 40 + seg * 4];
        floatx4 v1 = *(const floatx4*)&sw[co_l * 40 + 16 + seg * 4];
        int co = nt * 128 + wn * 64 + nf * 16 + co_l;
        float* orow = out + ((size_t)(bb * COo + co) << 12) + hw0;
        *(floatx4*)&orow[seg * 4]      = v0;
        *(floatx4*)&orow[16 + seg * 4] = v1;
    }
}

// ---------------------------------------------------------------------------
extern "C" void kernel_launch(void* const* d_in, const int* in_sizes, int n_in,
                              void* d_out, int out_size, void* d_ws, size_t ws_size,
                              hipStream_t stream)
{
    const float* x     = (const float*)d_in[0];
    const float* resid = (const float*)d_in[1];
    const float* off_w = (const float*)d_in[2];
    const float* off_b = (const float*)d_in[3];
    const float* mod_w = (const float*)d_in[4];
    const float* mod_b = (const float*)d_in[5];
    const float* reg_w = (const float*)d_in[6];
    float* out = (float*)d_out;

    float* ws = (float*)d_ws;
    float* off_buf   = ws + O_OFF;
    float* mask_buf  = ws + O_MASK;
    __hip_bfloat16* Wbf  = (__hip_bfloat16*)(ws + O_WBF);
    __hip_bfloat16* Wpk  = (__hip_bfloat16*)(ws + O_WPK);
    __hip_bfloat16* Abuf = (__hip_bfloat16*)(ws + O_A);
    __hip_bfloat16* xT   = (__hip_bfloat16*)(ws + O_XT);
    __hip_bfloat16* resT = (__hip_bfloat16*)(ws + O_RT);

    // fused transpose (2048 blocks) + weight pack (2304 blocks)
    prep_kernel<<<2048 + (CK * COo + 255) / 256, 256, 0, stream>>>(
        x, resid, reg_w, off_w, mod_w, xT, resT, Wbf, Wpk);

    convA2_kernel<<<512, 512, 0, stream>>>(xT, resT, Wpk, off_b, mod_b,
                                           off_buf, mask_buf);

    gather_kernel<<<BB * HH * 8, 256, 0, stream>>>(xT, off_buf, mask_buf, Abuf);

    gemm_kernel<<<256, 256, 0, stream>>>(Abuf, Wbf, out);
}

// Round 3
// 154.839 us; speedup vs baseline: 1.1199x; 1.0391x over previous
//
#include <hip/hip_runtime.h>
#include <hip/hip_bf16.h>
#include <math.h>

// Problem constants (B=2, C=256, H=W=64, Co=256, 3x3, stride1, pad1)
#define BB 2
#define CC 256
#define HH 64
#define WW 64
#define COo 256
#define HWs 4096
#define K2 9
#define CK 2304   // C*9

typedef __attribute__((ext_vector_type(4))) float floatx4;
typedef __attribute__((ext_vector_type(8))) short shortx8;   // 8 bf16

// ---- workspace layout (float units) ----
#define O_OFF   0          // final offset  B*18*4096 = 147456 f
#define O_MASK  147456     // final modulator B*9*4096 = 73728 f
#define O_WBF   221184     // reg_w bf16 [co][ck] = 294912 f
#define O_WPK   516096     // convA weights [g2][kc8][tap9][nf2][lane][8] = 73728 f
#define O_A     589824     // A matrix bf16 [pix 8192][ck 2304] = 9437184 f
#define O_XT    10027008   // x NHWC bf16 [b][y][x][c] = 1048576 f
#define O_RT    11075584   // residual NHWC bf16 = 1048576 f
// total = 12,124,160 floats = 48.5 MB

__device__ __forceinline__ void gll16(const __hip_bfloat16* g, __hip_bfloat16* l) {
    __builtin_amdgcn_global_load_lds(
        (const __attribute__((address_space(1))) unsigned int*)g,
        (__attribute__((address_space(3))) unsigned int*)l, 16, 0, 0);
}

__device__ __forceinline__ short f2bf(float v) {
    __hip_bfloat16 h = __float2bfloat16(v);
    return *reinterpret_cast<short*>(&h);
}

__device__ __forceinline__ float bf2f(short s) {
    unsigned u = ((unsigned)(unsigned short)s) << 16;
    return __builtin_bit_cast(float, u);
}

// ---------------------------------------------------------------------------
// K0: FUSED prep = transpose (blocks 0..2047) + weight pack (blocks 2048+).
// (verbatim from validated R11)
// ---------------------------------------------------------------------------
__global__ __launch_bounds__(256) void prep_kernel(
    const float* __restrict__ x,
    const float* __restrict__ residual,
    const float* __restrict__ reg_w,
    const float* __restrict__ off_w,
    const float* __restrict__ mod_w,
    __hip_bfloat16* __restrict__ xT,
    __hip_bfloat16* __restrict__ resT,
    __hip_bfloat16* __restrict__ Wbf,
    __hip_bfloat16* __restrict__ Wpk)
{
    int blk = blockIdx.x;
    int t = threadIdx.x;
    if (blk < 2048) {
        int sel = blk >> 10;             // 0 = x, 1 = residual
        int bk  = blk & 1023;            // ((b*64 + y)*8 + oc)
        int oc = bk & 7;
        int y  = (bk >> 3) & 63;
        int b  = bk >> 9;
        int wo = t & 63;
        int cg = t >> 6;
        int c0 = oc * 32 + cg * 8;
        const float* src = (sel ? residual : x)
                           + ((size_t)(b * CC + c0) * HH + y) * WW + wo;
        shortx8 pk;
#pragma unroll
        for (int j = 0; j < 8; ++j) pk[j] = f2bf(src[(size_t)j * HWs]);
        __hip_bfloat16* dst = sel ? resT : xT;
        *(shortx8*)(dst + ((size_t)b * 4096 + y * 64 + wo) * 256 + c0) = pk;
    } else {
        int idx = (blk - 2048) * 256 + t;
        if (idx < CK * COo) {
            Wbf[idx] = __float2bfloat16(reg_w[idx]);
        }
        if (idx < 147456) {
            int g    = idx / 73728;
            int rem  = idx % 73728;
            int kc   = rem / 9216;
            int r2   = rem % 9216;
            int tap  = r2 / 1024;
            int r3   = r2 & 1023;
            int nf   = r3 >> 9;
            int r4   = r3 & 511;
            int lane = r4 >> 3;
            int j    = r4 & 7;
            int c    = kc * 32 + (lane >> 4) * 8 + j;
            int n    = nf * 16 + (lane & 15);
            float v = 0.f;
            if (g == 0) { if (n < 18) v = off_w[((size_t)n * CC + c) * 9 + tap]; }
            else        { if (n < 9)  v = mod_w[((size_t)n * CC + c) * 9 + tap]; }
            Wpk[idx] = __float2bfloat16(v);
        }
    }
}

// ---------------------------------------------------------------------------
// K1: DIRECT offset+modulator conv. (verbatim from validated R11: 8-wave
// K-split, LDS reduction, 4 waves/SIMD)
// ---------------------------------------------------------------------------
__global__ __launch_bounds__(512) void convA2_kernel(
    const __hip_bfloat16* __restrict__ xT,
    const __hip_bfloat16* __restrict__ resT,
    const __hip_bfloat16* __restrict__ Wpk,
    const float* __restrict__ off_b,
    const float* __restrict__ mod_b,
    float* __restrict__ off_out,
    float* __restrict__ mask_out)
{
    int blk = blockIdx.x;
    int tile = blk & 127;
    int g = (blk >> 7) & 1;
    int b = blk >> 8;
    int t = threadIdx.x;
    int lane = t & 63;
    int w = t >> 6;                  // 0..7
    int ph = w & 1;                  // pixel half (16 pixels)
    int ks = w >> 1;                 // K quarter (kc pair)
    int ln = lane & 15;
    int quad = lane >> 4;

    const __hip_bfloat16* src = (g ? xT : resT) + (size_t)b * 4096 * 256;
    const __hip_bfloat16* wg  = Wpk + (size_t)g * 73728 + (size_t)ks * 2 * 9216;

    int pix = tile * 32 + ph * 16 + ln;   // this lane's A-row (pixel)
    int ho = pix >> 6, wo = pix & 63;

    floatx4 acc0 = (floatx4){0.f, 0.f, 0.f, 0.f};
    floatx4 acc1 = (floatx4){0.f, 0.f, 0.f, 0.f};

#pragma unroll
    for (int tap = 0; tap < 9; ++tap) {
        int ky = tap / 3, kx = tap % 3;
        int r  = ho + ky - 1;
        int cx = wo + kx - 1;
        bool v = (r >= 0) && (r < HH) && (cx >= 0) && (cx < WW);
        int hw = v ? (r * WW + cx) : 0;
        const __hip_bfloat16* abase = src + (size_t)hw * 256 + quad * 8 + ks * 64;
        const __hip_bfloat16* wbase = wg + (size_t)tap * 1024 + lane * 8;
#pragma unroll
        for (int kc = 0; kc < 2; ++kc) {
            shortx8 af = *(const shortx8*)(abase + kc * 32);
            if (!v) {
                shortx8 zf = {0,0,0,0,0,0,0,0};
                af = zf;
            }
            shortx8 b0 = *(const shortx8*)(wbase + (size_t)kc * 9216);
            shortx8 b1 = *(const shortx8*)(wbase + (size_t)kc * 9216 + 512);
            acc0 = __builtin_amdgcn_mfma_f32_16x16x32_bf16(af, b0, acc0, 0, 0, 0);
            acc1 = __builtin_amdgcn_mfma_f32_16x16x32_bf16(af, b1, acc1, 0, 0, 0);
        }
    }

    __shared__ float s_red[8][64][8];    // 16 KB
    *(floatx4*)&s_red[w][lane][0] = acc0;
    *(floatx4*)&s_red[w][lane][4] = acc1;
    __syncthreads();
    if (w < 2) {                         // w == ph, ks == 0
#pragma unroll
        for (int j = 0; j < 4; ++j) {
            acc0[j] = s_red[w][lane][j]     + s_red[w + 2][lane][j]
                    + s_red[w + 4][lane][j] + s_red[w + 6][lane][j];
            acc1[j] = s_red[w][lane][4 + j]     + s_red[w + 2][lane][4 + j]
                    + s_red[w + 4][lane][4 + j] + s_red[w + 6][lane][4 + j];
        }

#pragma unroll
        for (int nf = 0; nf < 2; ++nf) {
            floatx4 a = nf ? acc1 : acc0;
            int n = nf * 16 + ln;
#pragma unroll
            for (int i2 = 0; i2 < 4; ++i2) {
                int p = tile * 32 + w * 16 + quad * 4 + i2;
                if (g == 0) {
                    if (n < 18)
                        off_out[((size_t)b * 18 + n) * HWs + p] = a[i2] + off_b[n];
                } else {
                    if (n < 9) {
                        float z = a[i2] + mod_b[n];
                        mask_out[((size_t)b * 9 + n) * HWs + p] =
                            2.f / (1.f + __expf(-z));
                    }
                }
            }
        }
    }
}

// ---------------------------------------------------------------------------
// K2: deformable gather -> bf16 A [pix][ck]. (verbatim from validated R8)
// ---------------------------------------------------------------------------
__global__ __launch_bounds__(256) void gather_kernel(
    const __hip_bfloat16* __restrict__ xT,
    const float* __restrict__ off,
    const float* __restrict__ mask,
    __hip_bfloat16* __restrict__ A)
{
    int blk = blockIdx.x;            // ((b*64 + ho)*8 + cc)
    int cc = blk & 7;
    int ho = (blk >> 3) & 63;
    int b  = blk >> 9;
    int t  = threadIdx.x;
    int wo = t & 63;
    int cg = t >> 6;

    __shared__ int   s_idx[4][K2][64];
    __shared__ float s_w  [4][K2][64];

    for (int u = t; u < K2 * 64; u += 256) {
        int k = u >> 6;
        int wv = u & 63;
        float dy = off[((((size_t)b * 18 + 2 * k    ) * HH + ho) << 6) + wv];
        float dx = off[((((size_t)b * 18 + 2 * k + 1) * HH + ho) << 6) + wv];
        float m  = mask[((((size_t)b * 9 + k) * HH + ho) << 6) + wv];
        float py = (float)(ho - 1 + k / 3) + dy;
        float px = (float)(wv - 1 + k % 3) + dx;
        float y0f = floorf(py), x0f = floorf(px);
        float wy1 = py - y0f, wx1 = px - x0f;
        float wy0 = 1.f - wy1, wx0 = 1.f - wx1;
        int y0 = (int)y0f, x0 = (int)x0f;
#pragma unroll
        for (int j = 0; j < 4; ++j) {
            int yy = y0 + (j >> 1);
            int xx = x0 + (j & 1);
            float wj = ((j == 0) ? wy0 * wx0 :
                        (j == 1) ? wy0 * wx1 :
                        (j == 2) ? wy1 * wx0 : wy1 * wx1) * m;
            bool valid = (yy >= 0) && (yy < HH) && (xx >= 0) && (xx < WW);
            s_idx[j][k][wv] = valid ? (yy * WW + xx) : 0;
            s_w  [j][k][wv] = valid ? wj : 0.f;
        }
    }
    __syncthreads();

    const __hip_bfloat16* xb = xT + (size_t)b * 4096 * 256 + cc * 32 + cg * 8;

    shortx8 outv[9];
#pragma unroll
    for (int k = 0; k < K2; ++k) {
        int   i0 = s_idx[0][k][wo], i1 = s_idx[1][k][wo];
        int   i2 = s_idx[2][k][wo], i3 = s_idx[3][k][wo];
        float w0 = s_w[0][k][wo], w1 = s_w[1][k][wo];
        float w2 = s_w[2][k][wo], w3 = s_w[3][k][wo];
        shortx8 c0 = *(const shortx8*)(xb + (size_t)i0 * 256);
        shortx8 c1 = *(const shortx8*)(xb + (size_t)i1 * 256);
        shortx8 c2 = *(const shortx8*)(xb + (size_t)i2 * 256);
        shortx8 c3 = *(const shortx8*)(xb + (size_t)i3 * 256);
#pragma unroll
        for (int j = 0; j < 8; ++j) {
            float v = w0 * bf2f(c0[j]) + w1 * bf2f(c1[j])
                    + w2 * bf2f(c2[j]) + w3 * bf2f(c3[j]);
            int idx = j * 9 + k;
            outv[idx >> 3][idx & 7] = f2bf(v);
        }
    }

    __hip_bfloat16* arow = A + (size_t)((b * 64 + ho) * 64 + wo) * CK
                             + cc * 288 + cg * 72;
#pragma unroll
    for (int m = 0; m < 9; ++m)
        *(shortx8*)(arow + m * 8) = outv[m];
}

// ---------------------------------------------------------------------------
// K3: bf16 MFMA GEMM, R13.
// R12's raw-barrier triple-buffer FAILED validation (absmax 32 ~= all-zero
// output); reverted to the R8/R11-validated sync structure (one
// __syncthreads per K-step, double-buffered DMA prefetch, XOR k-chunk
// swizzle) -- bit-identical inner loop & accumulation order.
// R13 change: tile M 64->32 (grid 512, 2 blocks/CU min), LDS 58->45 KB
// (2x4 A + 2x16 B + 5 epilogue) -> 3 blocks/CU, 12 waves/CU = 3 waves/SIMD.
// Latency hiding now comes from co-resident blocks (m114: implicit wave
// overlap captures pipelining gains), not from hand-rolled vmcnt counting.
// Per wave: 16-row x 64-col output, acc[4], 8 MFMA per K-step.
// ---------------------------------------------------------------------------
__global__ __launch_bounds__(256) void gemm_kernel(
    const __hip_bfloat16* __restrict__ A,
    const __hip_bfloat16* __restrict__ Wbf,
    float* __restrict__ out)
{
    int blk0 = blockIdx.x;
    int blk = ((blk0 & 7) << 6) | (blk0 >> 3);   // XCD chunking, bijective on 512
    int nt = blk & 1;
    int mt = blk >> 1;              // 0..255 (32-pixel tiles)
    int t  = threadIdx.x;
    int lane = t & 63;
    int w    = t >> 6;              // 0..3
    int quad = lane >> 4;
    int ln   = lane & 15;
    int wm = w & 1;                 // M half (16 rows)
    int wn = w >> 1;                // N half (64 cols)

    __shared__ __hip_bfloat16 As[2][32 * 64];    // 2 x 4 KB
    __shared__ __hip_bfloat16 Bs[2][128 * 64];   // 2 x 16 KB
    __shared__ float s_out[4][16 * 20];          // per-wave epilogue (5 KB)

    int lr8 = lane >> 3;            // 0..7 (staging row within wave's 8)
    int sub = lane & 7;             // 16B slot within 128B row
    int chk = sub ^ lr8;            // global k-chunk this lane fetches

    const __hip_bfloat16* gA = A   + (size_t)(mt * 32 + w * 8 + lr8) * CK + chk * 8;
    const __hip_bfloat16* gB = Wbf + (size_t)(nt * 128 + w * 8 + lr8) * CK + chk * 8;
    int lof = w * 512;              // elements

    floatx4 acc[4];
#pragma unroll
    for (int nf = 0; nf < 4; ++nf) acc[nf] = (floatx4){0.f, 0.f, 0.f, 0.f};

    // prologue: stage buf0 (A: 1 DMA -> rows w*8..w*8+7; B: 4 DMAs -> +h*32)
    gll16(gA, &As[0][lof]);
#pragma unroll
    for (int h = 0; h < 4; ++h)
        gll16(gB + (size_t)(h * 32) * CK, &Bs[0][lof + h * 2048]);

    int swz = ln & 7;               // read-slot XOR key

    for (int kt = 0; kt < 36; ++kt) {
        int cur = kt & 1;
        int nxt = cur ^ 1;
        __syncthreads();                      // buf[cur] staged; buf[nxt] reads done
        if (kt + 1 < 36) {
            int ko = (kt + 1) * 64;
            gll16(gA + ko, &As[nxt][lof]);
#pragma unroll
            for (int h = 0; h < 4; ++h)
                gll16(gB + (size_t)(h * 32) * CK + ko, &Bs[nxt][lof + h * 2048]);
        }
#pragma unroll
        for (int kh = 0; kh < 2; ++kh) {
            int slot = ((kh * 4 + quad) ^ swz) * 8;
            shortx8 af = *(const shortx8*)
                &As[cur][(wm * 16 + ln) * 64 + slot];
            shortx8 bf[4];
#pragma unroll
            for (int nf = 0; nf < 4; ++nf)
                bf[nf] = *(const shortx8*)
                    &Bs[cur][(wn * 64 + nf * 16 + ln) * 64 + slot];
#pragma unroll
            for (int nf = 0; nf < 4; ++nf)
                acc[nf] = __builtin_amdgcn_mfma_f32_16x16x32_bf16(
                    af, bf[nf], acc[nf], 0, 0, 0);
        }
    }

    // epilogue: per-wave LDS transpose (region disjoint from As/Bs; no barrier)
    int bb = mt >> 7;
    int hw0 = (mt & 127) * 32 + wm * 16;
    float* sw = &s_out[w][0];
    int co_l = lane >> 2;
    int seg  = lane & 3;
#pragma unroll
    for (int nf = 0; nf < 4; ++nf) {
        *(floatx4*)&sw[ln * 20 + quad * 4] = acc[nf];
        floatx4 v0 = *(const floatx4*)&sw[co_l * 20 + seg * 4];
        int co = nt * 128 + wn * 64 + nf * 16 + co_l;
        float* orow = out + ((size_t)(bb * COo + co) << 12) + hw0;
        *(floatx4*)&orow[seg * 4] = v0;
    }
}

// ---------------------------------------------------------------------------
extern "C" void kernel_launch(void* const* d_in, const int* in_sizes, int n_in,
                              void* d_out, int out_size, void* d_ws, size_t ws_size,
                              hipStream_t stream)
{
    const float* x     = (const float*)d_in[0];
    const float* resid = (const float*)d_in[1];
    const float* off_w = (const float*)d_in[2];
    const float* off_b = (const float*)d_in[3];
    const float* mod_w = (const float*)d_in[4];
    const float* mod_b = (const float*)d_in[5];
    const float* reg_w = (const float*)d_in[6];
    float* out = (float*)d_out;

    float* ws = (float*)d_ws;
    float* off_buf   = ws + O_OFF;
    float* mask_buf  = ws + O_MASK;
    __hip_bfloat16* Wbf  = (__hip_bfloat16*)(ws + O_WBF);
    __hip_bfloat16* Wpk  = (__hip_bfloat16*)(ws + O_WPK);
    __hip_bfloat16* Abuf = (__hip_bfloat16*)(ws + O_A);
    __hip_bfloat16* xT   = (__hip_bfloat16*)(ws + O_XT);
    __hip_bfloat16* resT = (__hip_bfloat16*)(ws + O_RT);

    // fused transpose (2048 blocks) + weight pack (2304 blocks)
    prep_kernel<<<2048 + (CK * COo + 255) / 256, 256, 0, stream>>>(
        x, resid, reg_w, off_w, mod_w, xT, resT, Wbf, Wpk);

    convA2_kernel<<<512, 512, 0, stream>>>(xT, resT, Wpk, off_b, mod_b,
                                           off_buf, mask_buf);

    gather_kernel<<<BB * HH * 8, 256, 0, stream>>>(xT, off_buf, mask_buf, Abuf);

    gemm_kernel<<<512, 256, 0, stream>>>(Abuf, Wbf, out);
}

// Round 4
// 132.354 us; speedup vs baseline: 1.3101x; 1.1699x over previous
//
#include <hip/hip_runtime.h>
#include <hip/hip_bf16.h>
#include <math.h>

// Problem constants (B=2, C=256, H=W=64, Co=256, 3x3, stride1, pad1)
#define BB 2
#define CC 256
#define HH 64
#define WW 64
#define COo 256
#define HWs 4096
#define K2 9
#define CK 2304   // C*9

typedef __attribute__((ext_vector_type(4))) float floatx4;
typedef __attribute__((ext_vector_type(8))) short shortx8;   // 8 bf16

// ---- workspace layout (float units) ----
#define O_OFF   0          // final offset  B*18*4096 = 147456 f
#define O_MASK  147456     // final modulator B*9*4096 = 73728 f
#define O_WBF   221184     // reg_w bf16 [co][k*256+c] = 294912 f  (R14: tap-major)
#define O_WPK   516096     // convA weights [g2][kc8][tap9][nf2][lane][8] = 73728 f
#define O_A     589824     // (unused since R14 fusion)
#define O_XT    10027008   // x NHWC bf16 [b][y][x][c] = 1048576 f
#define O_RT    11075584   // residual NHWC bf16 = 1048576 f

__device__ __forceinline__ void gll16(const __hip_bfloat16* g, __hip_bfloat16* l) {
    __builtin_amdgcn_global_load_lds(
        (const __attribute__((address_space(1))) unsigned int*)g,
        (__attribute__((address_space(3))) unsigned int*)l, 16, 0, 0);
}

__device__ __forceinline__ short f2bf(float v) {
    __hip_bfloat16 h = __float2bfloat16(v);
    return *reinterpret_cast<short*>(&h);
}

__device__ __forceinline__ float bf2f(short s) {
    unsigned u = ((unsigned)(unsigned short)s) << 16;
    return __builtin_bit_cast(float, u);
}

// ---------------------------------------------------------------------------
// K0: FUSED prep = transpose (blocks 0..2047) + weight pack (blocks 2048+).
// R14: Wbf repacked TAP-MAJOR: Wbf[co*2304 + k*256 + c] = reg_w[co][c][k].
// (transpose + Wpk parts verbatim from validated R11)
// ---------------------------------------------------------------------------
__global__ __launch_bounds__(256) void prep_kernel(
    const float* __restrict__ x,
    const float* __restrict__ residual,
    const float* __restrict__ reg_w,
    const float* __restrict__ off_w,
    const float* __restrict__ mod_w,
    __hip_bfloat16* __restrict__ xT,
    __hip_bfloat16* __restrict__ resT,
    __hip_bfloat16* __restrict__ Wbf,
    __hip_bfloat16* __restrict__ Wpk)
{
    int blk = blockIdx.x;
    int t = threadIdx.x;
    if (blk < 2048) {
        int sel = blk >> 10;             // 0 = x, 1 = residual
        int bk  = blk & 1023;            // ((b*64 + y)*8 + oc)
        int oc = bk & 7;
        int y  = (bk >> 3) & 63;
        int b  = bk >> 9;
        int wo = t & 63;
        int cg = t >> 6;
        int c0 = oc * 32 + cg * 8;
        const float* src = (sel ? residual : x)
                           + ((size_t)(b * CC + c0) * HH + y) * WW + wo;
        shortx8 pk;
#pragma unroll
        for (int j = 0; j < 8; ++j) pk[j] = f2bf(src[(size_t)j * HWs]);
        __hip_bfloat16* dst = sel ? resT : xT;
        *(shortx8*)(dst + ((size_t)b * 4096 + y * 64 + wo) * 256 + c0) = pk;
    } else {
        int idx = (blk - 2048) * 256 + t;
        if (idx < CK * COo) {
            // dst (co, k, c) <- reg_w[co*2304 + c*9 + k]
            int co = idx / CK;
            int r  = idx - co * CK;
            int k  = r >> 8;
            int c  = r & 255;
            Wbf[idx] = __float2bfloat16(reg_w[(size_t)co * CK + c * 9 + k]);
        }
        if (idx < 147456) {
            int g    = idx / 73728;
            int rem  = idx % 73728;
            int kc   = rem / 9216;
            int r2   = rem % 9216;
            int tap  = r2 / 1024;
            int r3   = r2 & 1023;
            int nf   = r3 >> 9;
            int r4   = r3 & 511;
            int lane = r4 >> 3;
            int j    = r4 & 7;
            int c    = kc * 32 + (lane >> 4) * 8 + j;
            int n    = nf * 16 + (lane & 15);
            float v = 0.f;
            if (g == 0) { if (n < 18) v = off_w[((size_t)n * CC + c) * 9 + tap]; }
            else        { if (n < 9)  v = mod_w[((size_t)n * CC + c) * 9 + tap]; }
            Wpk[idx] = __float2bfloat16(v);
        }
    }
}

// ---------------------------------------------------------------------------
// K1: DIRECT offset+modulator conv. (verbatim from validated R11)
// ---------------------------------------------------------------------------
__global__ __launch_bounds__(512) void convA2_kernel(
    const __hip_bfloat16* __restrict__ xT,
    const __hip_bfloat16* __restrict__ resT,
    const __hip_bfloat16* __restrict__ Wpk,
    const float* __restrict__ off_b,
    const float* __restrict__ mod_b,
    float* __restrict__ off_out,
    float* __restrict__ mask_out)
{
    int blk = blockIdx.x;
    int tile = blk & 127;
    int g = (blk >> 7) & 1;
    int b = blk >> 8;
    int t = threadIdx.x;
    int lane = t & 63;
    int w = t >> 6;                  // 0..7
    int ph = w & 1;                  // pixel half (16 pixels)
    int ks = w >> 1;                 // K quarter (kc pair)
    int ln = lane & 15;
    int quad = lane >> 4;

    const __hip_bfloat16* src = (g ? xT : resT) + (size_t)b * 4096 * 256;
    const __hip_bfloat16* wg  = Wpk + (size_t)g * 73728 + (size_t)ks * 2 * 9216;

    int pix = tile * 32 + ph * 16 + ln;   // this lane's A-row (pixel)
    int ho = pix >> 6, wo = pix & 63;

    floatx4 acc0 = (floatx4){0.f, 0.f, 0.f, 0.f};
    floatx4 acc1 = (floatx4){0.f, 0.f, 0.f, 0.f};

#pragma unroll
    for (int tap = 0; tap < 9; ++tap) {
        int ky = tap / 3, kx = tap % 3;
        int r  = ho + ky - 1;
        int cx = wo + kx - 1;
        bool v = (r >= 0) && (r < HH) && (cx >= 0) && (cx < WW);
        int hw = v ? (r * WW + cx) : 0;
        const __hip_bfloat16* abase = src + (size_t)hw * 256 + quad * 8 + ks * 64;
        const __hip_bfloat16* wbase = wg + (size_t)tap * 1024 + lane * 8;
#pragma unroll
        for (int kc = 0; kc < 2; ++kc) {
            shortx8 af = *(const shortx8*)(abase + kc * 32);
            if (!v) {
                shortx8 zf = {0,0,0,0,0,0,0,0};
                af = zf;
            }
            shortx8 b0 = *(const shortx8*)(wbase + (size_t)kc * 9216);
            shortx8 b1 = *(const shortx8*)(wbase + (size_t)kc * 9216 + 512);
            acc0 = __builtin_amdgcn_mfma_f32_16x16x32_bf16(af, b0, acc0, 0, 0, 0);
            acc1 = __builtin_amdgcn_mfma_f32_16x16x32_bf16(af, b1, acc1, 0, 0, 0);
        }
    }

    __shared__ float s_red[8][64][8];    // 16 KB
    *(floatx4*)&s_red[w][lane][0] = acc0;
    *(floatx4*)&s_red[w][lane][4] = acc1;
    __syncthreads();
    if (w < 2) {                         // w == ph, ks == 0
#pragma unroll
        for (int j = 0; j < 4; ++j) {
            acc0[j] = s_red[w][lane][j]     + s_red[w + 2][lane][j]
                    + s_red[w + 4][lane][j] + s_red[w + 6][lane][j];
            acc1[j] = s_red[w][lane][4 + j]     + s_red[w + 2][lane][4 + j]
                    + s_red[w + 4][lane][4 + j] + s_red[w + 6][lane][4 + j];
        }

#pragma unroll
        for (int nf = 0; nf < 2; ++nf) {
            floatx4 a = nf ? acc1 : acc0;
            int n = nf * 16 + ln;
#pragma unroll
            for (int i2 = 0; i2 < 4; ++i2) {
                int p = tile * 32 + w * 16 + quad * 4 + i2;
                if (g == 0) {
                    if (n < 18)
                        off_out[((size_t)b * 18 + n) * HWs + p] = a[i2] + off_b[n];
                } else {
                    if (n < 9) {
                        float z = a[i2] + mod_b[n];
                        mask_out[((size_t)b * 9 + n) * HWs + p] =
                            2.f / (1.f + __expf(-z));
                    }
                }
            }
        }
    }
}

// ---------------------------------------------------------------------------
// K2 (R14): FUSED gather+GEMM. Replaces gather_kernel + gemm_kernel.
// Skeleton = validated R13 (grid 512 = mt256 x nt2, block 256 = 4 waves,
// one __syncthreads per K-step, dbuf B-DMA with pre-swizzled global src,
// XOR read swizzle, per-wave LDS epilogue). Change: A-subtile is GATHERED
// in-block per K-step instead of streamed from Abuf. K is tap-major
// (matches repacked Wbf): kt -> tap k = kt>>2, channel block cb = kt&3.
// Corner idx/weights per (pixel, tap) computed once into LDS (288 entries).
// Gather write uses storage swizzle (ch8 ^ (pix&7)) matching the read-side
// swz = ln&7 -> ds_read_b128 stays conflict-free.
// ---------------------------------------------------------------------------
__global__ __launch_bounds__(256) void gemm_fused_kernel(
    const __hip_bfloat16* __restrict__ xT,
    const float* __restrict__ off,
    const float* __restrict__ mask,
    const __hip_bfloat16* __restrict__ Wbf,
    float* __restrict__ out)
{
    int blk0 = blockIdx.x;
    int blk = ((blk0 & 7) << 6) | (blk0 >> 3);   // XCD chunking, bijective on 512
    int nt = blk & 1;
    int mt = blk >> 1;              // 0..255 (32-pixel tiles)
    int t  = threadIdx.x;
    int lane = t & 63;
    int w    = t >> 6;              // 0..3
    int quad = lane >> 4;
    int ln   = lane & 15;
    int wm = w & 1;                 // M half (16 rows)
    int wn = w >> 1;                // N half (64 cols)

    __shared__ __hip_bfloat16 As[2][32 * 64];    // 8 KB
    __shared__ __hip_bfloat16 Bs[2][128 * 64];   // 32 KB
    __shared__ int   s_mi[32][K2][4];            // 4.5 KB corner indices
    __shared__ float s_mw[32][K2][4];            // 4.5 KB corner weights (x mask)
    __shared__ float s_out[4][16 * 20];          // 5 KB epilogue
    // total 54 KB -> 2 blocks/CU

    int b = mt >> 7;
    const __hip_bfloat16* xb = xT + (size_t)b * 4096 * 256;

    int lr8 = lane >> 3;            // staging row within 8
    int sub = lane & 7;             // 16B slot
    int chk = sub ^ lr8;            // pre-swizzled global k-chunk

    const __hip_bfloat16* gB = Wbf + (size_t)(nt * 128 + w * 8 + lr8) * CK + chk * 8;
    int lof = w * 512;

    floatx4 acc[4];
#pragma unroll
    for (int nf = 0; nf < 4; ++nf) acc[nf] = (floatx4){0.f, 0.f, 0.f, 0.f};

    // issue B buf0 DMA first (latency overlaps meta compute)
#pragma unroll
    for (int h = 0; h < 4; ++h)
        gll16(gB + (size_t)(h * 32) * CK, &Bs[0][lof + h * 2048]);

    // ---- meta prologue: corner idx/weights for 32 pixels x 9 taps ----
    for (int u = t; u < 32 * K2; u += 256) {
        int pl = u / K2;
        int k  = u - pl * K2;
        int pix = mt * 32 + pl;
        int hw = pix & 4095;
        int ho = hw >> 6, wo = hw & 63;
        float dy = off [(((size_t)b * 18 + 2 * k    ) << 12) + hw];
        float dx = off [(((size_t)b * 18 + 2 * k + 1) << 12) + hw];
        float m  = mask[(((size_t)b * 9  + k        ) << 12) + hw];
        float py = (float)(ho - 1 + k / 3) + dy;
        float px = (float)(wo - 1 + k % 3) + dx;
        float y0f = floorf(py), x0f = floorf(px);
        float wy1 = py - y0f, wx1 = px - x0f;
        float wy0 = 1.f - wy1, wx0 = 1.f - wx1;
        int y0 = (int)y0f, x0 = (int)x0f;
#pragma unroll
        for (int j = 0; j < 4; ++j) {
            int yy = y0 + (j >> 1);
            int xx = x0 + (j & 1);
            float wj = ((j == 0) ? wy0 * wx0 :
                        (j == 1) ? wy0 * wx1 :
                        (j == 2) ? wy1 * wx0 : wy1 * wx1) * m;
            bool valid = (yy >= 0) && (yy < HH) && (xx >= 0) && (xx < WW);
            s_mi[pl][k][j] = valid ? (yy * WW + xx) : 0;
            s_mw[pl][k][j] = valid ? wj : 0.f;
        }
    }

    int pl  = t >> 3;               // gather: this thread's pixel (0..31)
    int ch8 = t & 7;                // gather: 8-channel group within 64
    int aslot = pl * 64 + ((ch8 ^ (pl & 7)) * 8);   // swizzled As column

    auto gather = [&](int buf, int kt1) {
        int k  = kt1 >> 2;
        int cb = kt1 & 3;
        int i0 = s_mi[pl][k][0], i1 = s_mi[pl][k][1];
        int i2 = s_mi[pl][k][2], i3 = s_mi[pl][k][3];
        float w0 = s_mw[pl][k][0], w1 = s_mw[pl][k][1];
        float w2 = s_mw[pl][k][2], w3 = s_mw[pl][k][3];
        const __hip_bfloat16* xr = xb + cb * 64 + ch8 * 8;
        shortx8 c0 = *(const shortx8*)(xr + (size_t)i0 * 256);
        shortx8 c1 = *(const shortx8*)(xr + (size_t)i1 * 256);
        shortx8 c2 = *(const shortx8*)(xr + (size_t)i2 * 256);
        shortx8 c3 = *(const shortx8*)(xr + (size_t)i3 * 256);
        shortx8 o;
#pragma unroll
        for (int j = 0; j < 8; ++j)
            o[j] = f2bf(w0 * bf2f(c0[j]) + w1 * bf2f(c1[j])
                      + w2 * bf2f(c2[j]) + w3 * bf2f(c3[j]));
        *(shortx8*)&As[buf][aslot] = o;
    };

    __syncthreads();                // meta visible (also drains B0 DMA)
    gather(0, 0);

    int swz = ln & 7;               // read-slot XOR key

    for (int kt = 0; kt < 36; ++kt) {
        int cur = kt & 1;
        int nxt = cur ^ 1;
        __syncthreads();            // buf[cur] staged; buf[nxt] reads done
        if (kt + 1 < 36) {
            int ko = (kt + 1) * 64;
#pragma unroll
            for (int h = 0; h < 4; ++h)
                gll16(gB + (size_t)(h * 32) * CK + ko, &Bs[nxt][lof + h * 2048]);
        }
#pragma unroll
        for (int kh = 0; kh < 2; ++kh) {
            int slot = ((kh * 4 + quad) ^ swz) * 8;
            shortx8 af = *(const shortx8*)
                &As[cur][(wm * 16 + ln) * 64 + slot];
            shortx8 bf[4];
#pragma unroll
            for (int nf = 0; nf < 4; ++nf)
                bf[nf] = *(const shortx8*)
                    &Bs[cur][(wn * 64 + nf * 16 + ln) * 64 + slot];
#pragma unroll
            for (int nf = 0; nf < 4; ++nf)
                acc[nf] = __builtin_amdgcn_mfma_f32_16x16x32_bf16(
                    af, bf[nf], acc[nf], 0, 0, 0);
        }
        if (kt + 1 < 36) gather(nxt, kt + 1);
    }

    // epilogue (verbatim R13): per-wave LDS transpose
    int bb = mt >> 7;
    int hw0 = (mt & 127) * 32 + wm * 16;
    float* sw = &s_out[w][0];
    int co_l = lane >> 2;
    int seg  = lane & 3;
#pragma unroll
    for (int nf = 0; nf < 4; ++nf) {
        *(floatx4*)&sw[ln * 20 + quad * 4] = acc[nf];
        floatx4 v0 = *(const floatx4*)&sw[co_l * 20 + seg * 4];
        int co = nt * 128 + wn * 64 + nf * 16 + co_l;
        float* orow = out + ((size_t)(bb * COo + co) << 12) + hw0;
        *(floatx4*)&orow[seg * 4] = v0;
    }
}

// ---------------------------------------------------------------------------
extern "C" void kernel_launch(void* const* d_in, const int* in_sizes, int n_in,
                              void* d_out, int out_size, void* d_ws, size_t ws_size,
                              hipStream_t stream)
{
    const float* x     = (const float*)d_in[0];
    const float* resid = (const float*)d_in[1];
    const float* off_w = (const float*)d_in[2];
    const float* off_b = (const float*)d_in[3];
    const float* mod_w = (const float*)d_in[4];
    const float* mod_b = (const float*)d_in[5];
    const float* reg_w = (const float*)d_in[6];
    float* out = (float*)d_out;

    float* ws = (float*)d_ws;
    float* off_buf   = ws + O_OFF;
    float* mask_buf  = ws + O_MASK;
    __hip_bfloat16* Wbf  = (__hip_bfloat16*)(ws + O_WBF);
    __hip_bfloat16* Wpk  = (__hip_bfloat16*)(ws + O_WPK);
    __hip_bfloat16* xT   = (__hip_bfloat16*)(ws + O_XT);
    __hip_bfloat16* resT = (__hip_bfloat16*)(ws + O_RT);

    // fused transpose (2048 blocks) + weight pack (2304 blocks)
    prep_kernel<<<2048 + (CK * COo + 255) / 256, 256, 0, stream>>>(
        x, resid, reg_w, off_w, mod_w, xT, resT, Wbf, Wpk);

    convA2_kernel<<<512, 512, 0, stream>>>(xT, resT, Wpk, off_b, mod_b,
                                           off_buf, mask_buf);

    gemm_fused_kernel<<<512, 256, 0, stream>>>(xT, off_buf, mask_buf, Wbf, out);
}